// Round 15
// baseline (233.814 us; speedup 1.0000x reference)
//
#include <hip/hip_runtime.h>
#include <hip/hip_bf16.h>
#include <math.h>

#define T_    100
#define D_    50
#define H_    30
#define HALF  5120
#define EMB_  20
#define NEMB_ 10
#define OUT_  10

typedef _Float16 h2    __attribute__((ext_vector_type(2)));
typedef _Float16 f16x8 __attribute__((ext_vector_type(8)));
typedef float    f32x4 __attribute__((ext_vector_type(4)));

union FR  { f16x8 v; h2 p[4]; float4 f4; };

__device__ __forceinline__ h2 pk(float a, float b) {
    return __builtin_bit_cast(h2, __builtin_amdgcn_cvt_pkrtz(a, b));
}
__device__ __forceinline__ int pki(float a, float b) {
    return __builtin_bit_cast(int, __builtin_amdgcn_cvt_pkrtz(a, b));
}

#define EXP2(x) exp2f(x)

struct XR { float2 a0, a1, a2, a3, b0, b1, b2, b3; };

// Row permutation: weight row (gate g, hidden j) stored at ge = g*32 + rho(j),
// rho(j) = (j&3) + 4*(j>>3) + 16*((j>>2)&1).  Lane (s = l&15, q = l>>4) then
// holds C-values for j = 8q + 4u + r — exactly its next-step B-frag k-slice.
__device__ __forceinline__ int rho(int j) {
    return (j & 3) + 4 * (j >> 3) + 16 * ((j >> 2) & 1);
}

// ---------------------------------------------------------------------------
// GRU round 15: TLP over lane efficiency.
// R5-R14 evidence: per-step elapsed ~3190 cyc vs ~450 issue cyc in EVERY
// 640-wave config — the stall is in-order dependency latency, unfixable
// within one wave (prefetch/vmcnt/shuffle-free/pipeline all falsified);
// the only variable that moved it was co-resident wave count (R12, R2/R4).
// So: 4 seqs/wave via s&3 duplication -> 2560 waves (2.5/SIMD), waves fill
// each other's bubbles. Duplicate lanes load duplicate addresses (deduped
// in L1, no extra HBM) and compute duplicate results (stores masked s<4).
// Block = 256 thr = 4 waves x 4 seqs; grid 640; LDS weight staging shared.
// Body = R13: shuffle-free rho rows, h in-lane, biases folded into MFMA,
// log2e folded into weights, branch-free clamped depth-8 x prefetch.
// ---------------------------------------------------------------------------
__global__ __launch_bounds__(256, 2) void gru_kernel(
    const float* __restrict__ input1, const float* __restrict__ input2,
    const float* __restrict__ W_ih,  const float* __restrict__ W_hh,
    const float* __restrict__ b_ih,  const float* __restrict__ b_hh,
    float* __restrict__ emb1_out,    // [5120][30]
    float* __restrict__ h2_out)      // [5120][30]
{
    const int tid  = threadIdx.x;
    const int lane = tid & 63;
    const int wv   = tid >> 6;           // wave 0..3
    const int s    = lane & 15;
    const int q    = lane >> 4;
    const int n    = blockIdx.x * 16 + wv * 4 + (s & 3);   // 4 seqs/wave, x4 dup

    __shared__ __align__(16) _Float16 Wst [96 * 64];  // W_ih ext (12 KB)
    __shared__ __align__(16) _Float16 Whst[96 * 32];  // W_hh ext (6 KB)

    const float SC_RZ = -1.4426950408889634f;   // -log2(e)
    const float SC_N  =  2.8853900817779268f;   // +2*log2(e)

    for (int i = tid; i < 1536; i += 256) ((unsigned long long*)Wst)[i]  = 0ull;
    for (int i = tid; i < 768;  i += 256) ((unsigned long long*)Whst)[i] = 0ull;
    __syncthreads();

    for (int i = 0; i < 18; ++i) {
        int idx = tid + i * 256;
        if (idx < 4500) {
            int rw = idx / 50, k = idx - rw * 50;
            int g  = rw / 30,  j = rw - g * 30;
            int ge = g * 32 + rho(j);
            float sc = (g < 2) ? SC_RZ : SC_N;
            Wst[ge * 64 + k] = (_Float16)(W_ih[idx] * sc);
        }
    }
    if (tid < 90) {
        int g = tid / 30, j = tid - g * 30;
        int ge = g * 32 + rho(j);
        float sc = (g < 2) ? SC_RZ : SC_N;
        Wst[ge * 64 + 50] = (_Float16)(b_ih[tid] * sc);
    }
    for (int i = 0; i < 11; ++i) {
        int idx = tid + i * 256;
        if (idx < 2700) {
            int rw = idx / 30, k = idx - rw * 30;
            int g  = rw / 30,  j = rw - g * 30;
            int ge = g * 32 + rho(j);
            float sc = (g < 2) ? SC_RZ : SC_N;
            Whst[ge * 32 + k] = (_Float16)(W_hh[idx] * sc);
        }
    }
    if (tid < 90) {
        int g = tid / 30, j = tid - g * 30;
        int ge = g * 32 + rho(j);
        float sc = (g < 2) ? SC_RZ : SC_N;
        Whst[ge * 32 + 30] = (_Float16)(b_hh[tid] * sc);
    }
    __syncthreads();

    FR wih[6][2], whh[6];
    #pragma unroll
    for (int nt = 0; nt < 6; ++nt) {
        wih[nt][0].f4 = *(const float4*)&Wst [(nt * 16 + s) * 64 + q * 8];
        wih[nt][1].f4 = *(const float4*)&Wst [(nt * 16 + s) * 64 + 32 + q * 8];
        whh[nt].f4    = *(const float4*)&Whst[(nt * 16 + s) * 32 + q * 8];
    }

    const float* xp = (n < HALF) ? input1 + (size_t)n * (T_ * D_)
                                 : input2 + (size_t)(n - HALF) * (T_ * D_);

    auto load_x = [&](int t, XR& X) {
        const float* r  = xp + t * D_;
        const float* pa = r + q * 8;
        const float* pb = (q < 2) ? (r + 32 + q * 8) : r;
        const float* p0 = (q == 2) ? (r + 48) : pb;
        X.a0 = *(const float2*)(pa + 0);
        X.a1 = *(const float2*)(pa + 2);
        X.a2 = *(const float2*)(pa + 4);
        X.a3 = *(const float2*)(pa + 6);
        X.b0 = *(const float2*)(p0);
        X.b1 = *(const float2*)(pb + 2);
        X.b2 = *(const float2*)(pb + 4);
        X.b3 = *(const float2*)(pb + 6);
    };
    auto build = [&](const XR& X, FR& x0, FR& x1) {
        x0.p[0] = pk(X.a0.x, X.a0.y); x0.p[1] = pk(X.a1.x, X.a1.y);
        x0.p[2] = pk(X.a2.x, X.a2.y); x0.p[3] = pk(X.a3.x, X.a3.y);
        if (q < 2) {
            x1.p[0] = pk(X.b0.x, X.b0.y); x1.p[1] = pk(X.b1.x, X.b1.y);
            x1.p[2] = pk(X.b2.x, X.b2.y); x1.p[3] = pk(X.b3.x, X.b3.y);
        } else if (q == 2) {
            x1.p[0] = pk(X.b0.x, X.b0.y); x1.p[1] = pk(1.f, 0.f);  // d48,49 | d50=bias
            x1.p[2] = pk(0.f, 0.f);       x1.p[3] = pk(0.f, 0.f);
        } else {
            x1.p[0] = pk(0.f, 0.f); x1.p[1] = pk(0.f, 0.f);
            x1.p[2] = pk(0.f, 0.f); x1.p[3] = pk(0.f, 0.f);
        }
    };

    float hold[8] = {0.f, 0.f, 0.f, 0.f, 0.f, 0.f, 0.f, 0.f};
    int w0 = 0, w1 = 0, w2 = 0, w3 = 0;   // packed h = next step's B-frag
    const int ONE = pki(1.f, 0.f);         // Hext k=30 bias column (q==3)

    auto step = [&](const FR& x0, const FR& x1) {
        FR bh;
        bh.p[0] = __builtin_bit_cast(h2, w0);
        bh.p[1] = __builtin_bit_cast(h2, w1);
        bh.p[2] = __builtin_bit_cast(h2, w2);
        bh.p[3] = __builtin_bit_cast(h2, q == 3 ? ONE : w3);

        f32x4 arz[4], anh[2], anx[2];
        #pragma unroll
        for (int nt = 0; nt < 4; ++nt) {
            f32x4 acc = {0.f, 0.f, 0.f, 0.f};
            acc = __builtin_amdgcn_mfma_f32_16x16x32_f16(wih[nt][0].v, x0.v, acc, 0, 0, 0);
            acc = __builtin_amdgcn_mfma_f32_16x16x32_f16(wih[nt][1].v, x1.v, acc, 0, 0, 0);
            acc = __builtin_amdgcn_mfma_f32_16x16x32_f16(whh[nt].v,    bh.v, acc, 0, 0, 0);
            arz[nt] = acc;
        }
        #pragma unroll
        for (int u = 0; u < 2; ++u) {
            f32x4 ax = {0.f, 0.f, 0.f, 0.f}, ah = {0.f, 0.f, 0.f, 0.f};
            ax = __builtin_amdgcn_mfma_f32_16x16x32_f16(wih[4 + u][0].v, x0.v, ax, 0, 0, 0);
            ax = __builtin_amdgcn_mfma_f32_16x16x32_f16(wih[4 + u][1].v, x1.v, ax, 0, 0, 0);
            ah = __builtin_amdgcn_mfma_f32_16x16x32_f16(whh[4 + u].v,    bh.v, ah, 0, 0, 0);
            anh[u] = ah; anx[u] = ax;
        }
        #pragma unroll
        for (int u = 0; u < 2; ++u) {
            #pragma unroll
            for (int r = 0; r < 4; ++r) {
                const float rg = __builtin_amdgcn_rcpf(1.f + EXP2(arz[u][r]));
                const float zg = __builtin_amdgcn_rcpf(1.f + EXP2(arz[2 + u][r]));
                const float aa = fmaf(rg, anh[u][r], anx[u][r]);
                const float th = fmaf(-2.f, __builtin_amdgcn_rcpf(1.f + EXP2(aa)), 1.f);
                hold[u * 4 + r] = fmaf(zg, hold[u * 4 + r] - th, th);
            }
        }
        w0 = pki(hold[0], hold[1]); w1 = pki(hold[2], hold[3]);
        w2 = pki(hold[4], hold[5]); w3 = pki(hold[6], hold[7]);
    };

    // ---- 100 steps, depth-8 branch-free software pipeline on x loads ----
    XR X0, X1, X2, X3, X4, X5, X6, X7;
    load_x(0, X0); load_x(1, X1); load_x(2, X2); load_x(3, X3);
    load_x(4, X4); load_x(5, X5); load_x(6, X6); load_x(7, X7);
    #pragma unroll 1
    for (int k = 0; k < 12; ++k) {
        const int t = 8 * k;
        FR x0, x1;
        build(X0, x0, x1); load_x(t +  8 < 100 ? t +  8 : 99, X0); step(x0, x1);
        build(X1, x0, x1); load_x(t +  9 < 100 ? t +  9 : 99, X1); step(x0, x1);
        build(X2, x0, x1); load_x(t + 10 < 100 ? t + 10 : 99, X2); step(x0, x1);
        build(X3, x0, x1); load_x(t + 11 < 100 ? t + 11 : 99, X3); step(x0, x1);
        build(X4, x0, x1); load_x(t + 12 < 100 ? t + 12 : 99, X4); step(x0, x1);
        build(X5, x0, x1); load_x(t + 13 < 100 ? t + 13 : 99, X5); step(x0, x1);
        build(X6, x0, x1); load_x(t + 14 < 100 ? t + 14 : 99, X6); step(x0, x1);
        build(X7, x0, x1); load_x(t + 15 < 100 ? t + 15 : 99, X7); step(x0, x1);
    }
    {   // tail: t = 96..99, loaded during k=11 into X0..X3
        FR x0, x1;
        build(X0, x0, x1); step(x0, x1);
        build(X1, x0, x1); step(x0, x1);
        build(X2, x0, x1); step(x0, x1);
        build(X3, x0, x1); step(x0, x1);
    }

    // ---- final hidden out: lane (s,q) holds h[j = 8q + 4u + r]; only the
    //      first copy of each seq (s < 4) stores ----
    if (s < 4) {
        float* outp = (n < HALF) ? emb1_out + (size_t)n * H_
                                 : h2_out + (size_t)(n - HALF) * H_;
        #pragma unroll
        for (int u = 0; u < 2; ++u)
            #pragma unroll
            for (int r = 0; r < 4; ++r) {
                const int j = 8 * q + 4 * u + r;
                if (j < H_) outp[j] = hold[u * 4 + r];
            }
    }
}

// ---------------------------------------------------------------------------
__global__ __launch_bounds__(64) void mlp_kernel(
    const float* __restrict__ h2i,
    const float* __restrict__ W1, const float* __restrict__ b1,
    const float* __restrict__ W2, const float* __restrict__ b2,
    const float* __restrict__ W3, const float* __restrict__ b3,
    float* __restrict__ logit)
{
    const int b    = blockIdx.x;
    const int lane = threadIdx.x;
    __shared__ float e2[300];
    const float* row = h2i + (size_t)b * 300;
    #pragma unroll
    for (int i = lane; i < 75; i += 64)
        *(float4*)&e2[i * 4] = *(const float4*)(row + i * 4);
    __syncthreads();

    const float kInvSqrt2 = 0.70710678118654752f;
    float y1 = 0.f;
    if (lane < EMB_) {
        float acc = b1[lane];
        const float* wp = W1 + lane * 300;
        #pragma unroll
        for (int qq = 0; qq < 75; ++qq) {
            float4 wv = *(const float4*)(wp + qq * 4);
            acc += wv.x * e2[qq*4 + 0] + wv.y * e2[qq*4 + 1]
                 + wv.z * e2[qq*4 + 2] + wv.w * e2[qq*4 + 3];
        }
        y1 = 0.5f * acc * (1.f + erff(acc * kInvSqrt2));
    }
    float acc2 = (lane < NEMB_) ? b2[lane] : 0.f;
    #pragma unroll
    for (int e = 0; e < EMB_; ++e) {
        const float v = __shfl(y1, e);
        if (lane < NEMB_) acc2 += v * W2[lane * EMB_ + e];
    }
    const float y2 = 0.5f * acc2 * (1.f + erff(acc2 * kInvSqrt2));
    float acc3 = (lane < OUT_) ? b3[lane] : 0.f;
    #pragma unroll
    for (int e = 0; e < NEMB_; ++e) {
        const float v = __shfl(y2, e);
        if (lane < OUT_) acc3 += v * W3[lane * NEMB_ + e];
    }
    if (lane < OUT_) logit[(size_t)b * OUT_ + lane] = acc3;
}

// ---------------------------------------------------------------------------
extern "C" void kernel_launch(void* const* d_in, const int* in_sizes, int n_in,
                              void* d_out, int out_size, void* d_ws, size_t ws_size,
                              hipStream_t stream) {
    const float* input1 = (const float*)d_in[0];
    const float* input2 = (const float*)d_in[1];
    const float* W_ih   = (const float*)d_in[2];
    const float* W_hh   = (const float*)d_in[3];
    const float* b_ih   = (const float*)d_in[4];
    const float* b_hh   = (const float*)d_in[5];
    const float* W1     = (const float*)d_in[6];
    const float* b1     = (const float*)d_in[7];
    const float* W2     = (const float*)d_in[8];
    const float* b2     = (const float*)d_in[9];
    const float* W3     = (const float*)d_in[10];
    const float* b3     = (const float*)d_in[11];

    float* out = (float*)d_out;
    float* h2s = (float*)d_ws;

    hipLaunchKernelGGL(gru_kernel, dim3(640), dim3(256), 0, stream,
                       input1, input2, W_ih, W_hh, b_ih, b_hh,
                       out + 5120, h2s);
    hipLaunchKernelGGL(mlp_kernel, dim3(512), dim3(64), 0, stream,
                       h2s, W1, b1, W2, b2, W3, b3, out);
}

// Round 16
// 101.846 us; speedup vs baseline: 2.2958x; 2.2958x over previous
//
#include <hip/hip_runtime.h>
#include <hip/hip_bf16.h>
#include <math.h>

#define T_    100
#define D_    50
#define H_    30
#define HALF  5120
#define EMB_  20
#define NEMB_ 10
#define OUT_  10

typedef _Float16 h2    __attribute__((ext_vector_type(2)));
typedef _Float16 f16x8 __attribute__((ext_vector_type(8)));
typedef float    f32x4 __attribute__((ext_vector_type(4)));

union FR  { f16x8 v; h2 p[4]; float4 f4; };

__device__ __forceinline__ h2 pk(float a, float b) {
    return __builtin_bit_cast(h2, __builtin_amdgcn_cvt_pkrtz(a, b));
}
__device__ __forceinline__ int pki(float a, float b) {
    return __builtin_bit_cast(int, __builtin_amdgcn_cvt_pkrtz(a, b));
}

#if __has_builtin(__builtin_amdgcn_exp2f)
#define EXP2(x) __builtin_amdgcn_exp2f(x)
#else
#define EXP2(x) exp2f(x)
#endif

struct XR { float2 a0, a1, a2, a3, b0, b1, b2, b3; };

// Row permutation: weight row (gate g, hidden j) stored at ge = g*32 + rho(j),
// rho(j) = (j&3) + 4*(j>>3) + 16*((j>>2)&1).  Lane (s = l&15, q = l>>4) then
// holds C-values for j = 8q + 4u + r — exactly its next-step B-frag k-slice.
__device__ __forceinline__ int rho(int j) {
    return (j & 3) + 4 * (j >> 3) + 16 * ((j >> 2) & 1);
}

// ---------------------------------------------------------------------------
// GRU: 1 wave per block, 16 seqs/wave, 640 blocks. Shuffle-free (rho rows).
// Round 16 = R14 (split-accumulator cross-step pipeline) + transcendental
// reduction: merged rcp for z-sigmoid and tanh (5 trans/element instead of
// 6 -> 40/step) and guaranteed v_exp_f32 via __builtin_amdgcn_exp2f.
// Rationale: per-wave VALU-execute ~890 cyc/step, ~384 of it the 48 trans
// ops at quarter rate; issue is the only remaining legal lever at 640 waves
// (TLP-duplication falsified in R15: packing gain < duplication cost).
// ---------------------------------------------------------------------------
__global__ __launch_bounds__(64, 1) void gru_kernel(
    const float* __restrict__ input1, const float* __restrict__ input2,
    const float* __restrict__ W_ih,  const float* __restrict__ W_hh,
    const float* __restrict__ b_ih,  const float* __restrict__ b_hh,
    float* __restrict__ emb1_out,    // [5120][30]
    float* __restrict__ h2_out)      // [5120][30]
{
    const int lane = threadIdx.x & 63;
    const int s    = lane & 15;
    const int q    = lane >> 4;
    const int n    = blockIdx.x * 16 + s;

    __shared__ __align__(16) _Float16 Wst [96 * 64];  // W_ih ext (12 KB)
    __shared__ __align__(16) _Float16 Whst[96 * 32];  // W_hh ext (6 KB)

    const float SC_RZ = -1.4426950408889634f;   // -log2(e)
    const float SC_N  =  2.8853900817779268f;   // +2*log2(e)

    for (int i = lane; i < 1536; i += 64) ((unsigned long long*)Wst)[i]  = 0ull;
    for (int i = lane; i < 768;  i += 64) ((unsigned long long*)Whst)[i] = 0ull;

    for (int i = 0; i < 71; ++i) {
        int idx = lane + i * 64;
        if (idx < 4500) {
            int rw = idx / 50, k = idx - rw * 50;
            int g  = rw / 30,  j = rw - g * 30;
            int ge = g * 32 + rho(j);
            float sc = (g < 2) ? SC_RZ : SC_N;
            Wst[ge * 64 + k] = (_Float16)(W_ih[idx] * sc);
        }
    }
    for (int i = 0; i < 2; ++i) {
        int idx = lane + i * 64;
        if (idx < 90) {
            int g = idx / 30, j = idx - g * 30;
            int ge = g * 32 + rho(j);
            float sc = (g < 2) ? SC_RZ : SC_N;
            Wst[ge * 64 + 50] = (_Float16)(b_ih[idx] * sc);
        }
    }
    for (int i = 0; i < 43; ++i) {
        int idx = lane + i * 64;
        if (idx < 2700) {
            int rw = idx / 30, k = idx - rw * 30;
            int g  = rw / 30,  j = rw - g * 30;
            int ge = g * 32 + rho(j);
            float sc = (g < 2) ? SC_RZ : SC_N;
            Whst[ge * 32 + k] = (_Float16)(W_hh[idx] * sc);
        }
    }
    for (int i = 0; i < 2; ++i) {
        int idx = lane + i * 64;
        if (idx < 90) {
            int g = idx / 30, j = idx - g * 30;
            int ge = g * 32 + rho(j);
            float sc = (g < 2) ? SC_RZ : SC_N;
            Whst[ge * 32 + 30] = (_Float16)(b_hh[idx] * sc);
        }
    }
    __syncthreads();

    FR wih[6][2], whh[6];
    #pragma unroll
    for (int nt = 0; nt < 6; ++nt) {
        wih[nt][0].f4 = *(const float4*)&Wst [(nt * 16 + s) * 64 + q * 8];
        wih[nt][1].f4 = *(const float4*)&Wst [(nt * 16 + s) * 64 + 32 + q * 8];
        whh[nt].f4    = *(const float4*)&Whst[(nt * 16 + s) * 32 + q * 8];
    }

    const float* xp = (n < HALF) ? input1 + (size_t)n * (T_ * D_)
                                 : input2 + (size_t)(n - HALF) * (T_ * D_);

    auto load_x = [&](int t, XR& X) {
        const float* r  = xp + t * D_;
        const float* pa = r + q * 8;
        const float* pb = (q < 2) ? (r + 32 + q * 8) : r;
        const float* p0 = (q == 2) ? (r + 48) : pb;
        X.a0 = *(const float2*)(pa + 0);
        X.a1 = *(const float2*)(pa + 2);
        X.a2 = *(const float2*)(pa + 4);
        X.a3 = *(const float2*)(pa + 6);
        X.b0 = *(const float2*)(p0);
        X.b1 = *(const float2*)(pb + 2);
        X.b2 = *(const float2*)(pb + 4);
        X.b3 = *(const float2*)(pb + 6);
    };
    auto build = [&](const XR& X, FR& x0, FR& x1) {
        x0.p[0] = pk(X.a0.x, X.a0.y); x0.p[1] = pk(X.a1.x, X.a1.y);
        x0.p[2] = pk(X.a2.x, X.a2.y); x0.p[3] = pk(X.a3.x, X.a3.y);
        if (q < 2) {
            x1.p[0] = pk(X.b0.x, X.b0.y); x1.p[1] = pk(X.b1.x, X.b1.y);
            x1.p[2] = pk(X.b2.x, X.b2.y); x1.p[3] = pk(X.b3.x, X.b3.y);
        } else if (q == 2) {
            x1.p[0] = pk(X.b0.x, X.b0.y); x1.p[1] = pk(1.f, 0.f);  // d48,49 | d50=bias
            x1.p[2] = pk(0.f, 0.f);       x1.p[3] = pk(0.f, 0.f);
        } else {
            x1.p[0] = pk(0.f, 0.f); x1.p[1] = pk(0.f, 0.f);
            x1.p[2] = pk(0.f, 0.f); x1.p[3] = pk(0.f, 0.f);
        }
    };

    float hold[8] = {0.f, 0.f, 0.f, 0.f, 0.f, 0.f, 0.f, 0.f};
    int w0 = 0, w1 = 0, w2 = 0, w3 = 0;   // packed h = next step's B-frag
    const int ONE = pki(1.f, 0.f);         // Hext k=30 bias column (q==3)

    // ---- x-phase: build frags from buffer, reload buffer, 12 x-MFMAs ----
    auto xphase = [&](XR& X, int tload, f32x4 (&xacc)[6]) {
        FR x0, x1;
        build(X, x0, x1);
        load_x(tload, X);
        #pragma unroll
        for (int i = 0; i < 6; ++i) {
            f32x4 zz = {0.f, 0.f, 0.f, 0.f};
            f32x4 a = __builtin_amdgcn_mfma_f32_16x16x32_f16(wih[i][0].v, x0.v, zz, 0, 0, 0);
            xacc[i] = __builtin_amdgcn_mfma_f32_16x16x32_f16(wih[i][1].v, x1.v, a, 0, 0, 0);
        }
    };
    // ---- h-phase: ONE MFMA per acc on the serial path (C-in = xacc) ----
    auto step_h = [&](const f32x4 (&xacc)[6], f32x4 (&arz)[4], f32x4 (&ah)[2]) {
        FR bh;
        bh.p[0] = __builtin_bit_cast(h2, w0);
        bh.p[1] = __builtin_bit_cast(h2, w1);
        bh.p[2] = __builtin_bit_cast(h2, w2);
        bh.p[3] = __builtin_bit_cast(h2, q == 3 ? ONE : w3);
        #pragma unroll
        for (int nt = 0; nt < 4; ++nt)
            arz[nt] = __builtin_amdgcn_mfma_f32_16x16x32_f16(whh[nt].v, bh.v, xacc[nt], 0, 0, 0);
        #pragma unroll
        for (int u = 0; u < 2; ++u) {
            f32x4 zz = {0.f, 0.f, 0.f, 0.f};
            ah[u] = __builtin_amdgcn_mfma_f32_16x16x32_f16(whh[4 + u].v, bh.v, zz, 0, 0, 0);
        }
    };
    // ---- gates + pack: 5 trans/element (merged z/tanh rcp) ----
    auto step_fin = [&](const f32x4 (&arz)[4], const f32x4 (&ah)[2],
                        const f32x4 (&xacc)[6]) {
        #pragma unroll
        for (int u = 0; u < 2; ++u) {
            #pragma unroll
            for (int r = 0; r < 4; ++r) {
                const float er = EXP2(arz[u][r]);                 // pre-scaled -log2e
                const float rg = __builtin_amdgcn_rcpf(1.f + er); // sigmoid(r)
                const float ez = EXP2(arz[2 + u][r]);
                const float aa = fmaf(rg, ah[u][r], xacc[4 + u][r]); // pre-scaled +2log2e
                const float et = EXP2(aa);
                const float oz = 1.f + ez, ot = 1.f + et;
                const float ip = __builtin_amdgcn_rcpf(oz * ot);  // merged rcp
                const float zg = ot * ip;                         // 1/(1+ez)
                const float th = fmaf(-2.f * oz, ip, 1.f);        // tanh
                hold[u * 4 + r] = fmaf(zg, hold[u * 4 + r] - th, th);
            }
        }
        w0 = pki(hold[0], hold[1]); w1 = pki(hold[2], hold[3]);
        w2 = pki(hold[4], hold[5]); w3 = pki(hold[6], hold[7]);
    };

    // ---- prologue: buffers hold x(0..3); xaccA for step 0; X0 -> x(4) ----
    XR X0, X1, X2, X3;
    load_x(0, X0); load_x(1, X1); load_x(2, X2); load_x(3, X3);
    f32x4 xaccA[6], xaccB[6];
    {
        FR x0, x1;
        build(X0, x0, x1);
        load_x(4, X0);
        #pragma unroll
        for (int i = 0; i < 6; ++i) {
            f32x4 zz = {0.f, 0.f, 0.f, 0.f};
            f32x4 a = __builtin_amdgcn_mfma_f32_16x16x32_f16(wih[i][0].v, x0.v, zz, 0, 0, 0);
            xaccA[i] = __builtin_amdgcn_mfma_f32_16x16x32_f16(wih[i][1].v, x1.v, a, 0, 0, 0);
        }
    }

    // ---- 100 steps: 25 x 4-step body; buffer m holds x(t) with t%4==m ----
    #pragma unroll 1
    for (int k = 0; k < 25; ++k) {
        const int t = 4 * k;
        f32x4 arz[4], ah[2];
        step_h(xaccA, arz, ah);
        xphase(X1, (t + 5 < 100 ? t + 5 : 99), xaccB);
        step_fin(arz, ah, xaccA);
        step_h(xaccB, arz, ah);
        xphase(X2, (t + 6 < 100 ? t + 6 : 99), xaccA);
        step_fin(arz, ah, xaccB);
        step_h(xaccA, arz, ah);
        xphase(X3, (t + 7 < 100 ? t + 7 : 99), xaccB);
        step_fin(arz, ah, xaccA);
        step_h(xaccB, arz, ah);
        xphase(X0, (t + 8 < 100 ? t + 8 : 99), xaccA);
        step_fin(arz, ah, xaccB);
    }

    // ---- final hidden out: lane (s,q) holds h[j = 8q + 4u + r] ----
    float* outp = (n < HALF) ? emb1_out + (size_t)n * H_
                             : h2_out + (size_t)(n - HALF) * H_;
    #pragma unroll
    for (int u = 0; u < 2; ++u)
        #pragma unroll
        for (int r = 0; r < 4; ++r) {
            const int j = 8 * q + 4 * u + r;
            if (j < H_) outp[j] = hold[u * 4 + r];
        }
}

// ---------------------------------------------------------------------------
__global__ __launch_bounds__(64) void mlp_kernel(
    const float* __restrict__ h2i,
    const float* __restrict__ W1, const float* __restrict__ b1,
    const float* __restrict__ W2, const float* __restrict__ b2,
    const float* __restrict__ W3, const float* __restrict__ b3,
    float* __restrict__ logit)
{
    const int b    = blockIdx.x;
    const int lane = threadIdx.x;
    __shared__ float e2[300];
    const float* row = h2i + (size_t)b * 300;
    #pragma unroll
    for (int i = lane; i < 75; i += 64)
        *(float4*)&e2[i * 4] = *(const float4*)(row + i * 4);
    __syncthreads();

    const float kInvSqrt2 = 0.70710678118654752f;
    float y1 = 0.f;
    if (lane < EMB_) {
        float acc = b1[lane];
        const float* wp = W1 + lane * 300;
        #pragma unroll
        for (int qq = 0; qq < 75; ++qq) {
            float4 wv = *(const float4*)(wp + qq * 4);
            acc += wv.x * e2[qq*4 + 0] + wv.y * e2[qq*4 + 1]
                 + wv.z * e2[qq*4 + 2] + wv.w * e2[qq*4 + 3];
        }
        y1 = 0.5f * acc * (1.f + erff(acc * kInvSqrt2));
    }
    float acc2 = (lane < NEMB_) ? b2[lane] : 0.f;
    #pragma unroll
    for (int e = 0; e < EMB_; ++e) {
        const float v = __shfl(y1, e);
        if (lane < NEMB_) acc2 += v * W2[lane * EMB_ + e];
    }
    const float y2 = 0.5f * acc2 * (1.f + erff(acc2 * kInvSqrt2));
    float acc3 = (lane < OUT_) ? b3[lane] : 0.f;
    #pragma unroll
    for (int e = 0; e < NEMB_; ++e) {
        const float v = __shfl(y2, e);
        if (lane < OUT_) acc3 += v * W3[lane * NEMB_ + e];
    }
    if (lane < OUT_) logit[(size_t)b * OUT_ + lane] = acc3;
}

// ---------------------------------------------------------------------------
extern "C" void kernel_launch(void* const* d_in, const int* in_sizes, int n_in,
                              void* d_out, int out_size, void* d_ws, size_t ws_size,
                              hipStream_t stream) {
    const float* input1 = (const float*)d_in[0];
    const float* input2 = (const float*)d_in[1];
    const float* W_ih   = (const float*)d_in[2];
    const float* W_hh   = (const float*)d_in[3];
    const float* b_ih   = (const float*)d_in[4];
    const float* b_hh   = (const float*)d_in[5];
    const float* W1     = (const float*)d_in[6];
    const float* b1     = (const float*)d_in[7];
    const float* W2     = (const float*)d_in[8];
    const float* b2     = (const float*)d_in[9];
    const float* W3     = (const float*)d_in[10];
    const float* b3     = (const float*)d_in[11];

    float* out = (float*)d_out;
    float* h2s = (float*)d_ws;

    hipLaunchKernelGGL(gru_kernel, dim3(640), dim3(64), 0, stream,
                       input1, input2, W_ih, W_hh, b_ih, b_hh,
                       out + 5120, h2s);
    hipLaunchKernelGGL(mlp_kernel, dim3(512), dim3(64), 0, stream,
                       h2s, W1, b1, W2, b2, W3, b3, out);
}